// Round 5
// baseline (587.065 us; speedup 1.0000x reference)
//
#include <hip/hip_runtime.h>

#define BB 4
#define CC 128
#define HH 128
#define WW 128
#define HW (HH*WW)
#define CHW (CC*HW)
#define ND 81
#define CP 136      // c-stride (shorts) for uc/fgs: 272 B rows -> 16B aligned, 2-way-free b128 reads
#define UPITCH 40   // u-stride (shorts) for cu: 80 B rows = 5x16B -> b128-aligned
#define PP 40       // P tile u stride (shorts): 80 B rows -> conflict-free pa reads/writes

typedef short s8v __attribute__((ext_vector_type(8)));   // 8 bf16 MFMA A/B frag
typedef short s4v __attribute__((ext_vector_type(4)));
typedef float f4v __attribute__((ext_vector_type(4)));   // MFMA C/D frag

__device__ __forceinline__ short f2bf(float x){          // RNE float->bf16 bits
  unsigned u = __float_as_uint(x);
  unsigned r = (u + 0x7FFFu + ((u >> 16) & 1u)) >> 16;
  return (short)r;
}
__device__ __forceinline__ float bf2f(short s){
  return __uint_as_float(((unsigned)(unsigned short)s) << 16);
}

// ---------------------------------------------------------------------------
// coef: paired sign-case tables, interleaved so the 3 cases hit different
// banks and one b64 gather fetches both values:
//   coef[(d*3+case)*2 + 0] = g2 = ga^2,  [..+1] = gt = ga*vp*t
//   ga = vp (s>0), vp*wm (s<0), vp*ah (s==0)    [a_lo+a_hi=1, a_hi-a_lo=wm]
// mapped m = g2*s - gt exactly; den elem = g2*t*t.
// [500]=step_length, [501]=reg_weight
// ---------------------------------------------------------------------------
__global__ void coef_kernel(const float* lw, const float* sw, const float* mw,
                            const float* lsl, const float* fr, float* coef){
  int d = threadIdx.x;
  if (d < ND){
    float dy = (float)(d / 9) - 4.0f;
    float dx = (float)(d % 9) - 4.0f;
    float dist = sqrtf(dy*dy + dx*dx) * 2.0f;
    float t = 0.f, v = 0.f, m = 0.f;
    for (int k = 0; k < 10; k++){
      float bd = dist - (float)k;
      float val = (k == 9) ? fminf(fmaxf(bd + 1.0f, 0.f), 1.f)
                           : fmaxf(1.0f - fabsf(bd), 0.f);
      t += val * lw[k]; v += val * sw[k]; m += val * mw[k];
    }
    float wm = 1.f / (1.f + expf(-m));
    float ah = (1.f + wm) * 0.5f;
    float gp = v, gn = v * wm, gz = v * ah;   // ga per sign case
    float vt = v * t;
    coef[(d*3+0)*2+0] = gp * gp;  coef[(d*3+0)*2+1] = gp * vt;
    coef[(d*3+1)*2+0] = gn * gn;  coef[(d*3+1)*2+1] = gn * vt;
    coef[(d*3+2)*2+0] = gz * gz;  coef[(d*3+2)*2+1] = gz * vt;
  }
  if (threadIdx.x == 0){
    coef[500] = expf(lsl[0]);
    float f = fr[0];
    coef[501] = fmaxf(f*f, 1e-10f) / (float)(CC*CC);
  }
}

// ---------------------------------------------------------------------------
// one-time convert: ref fp32 [b][c][h][w] ->
//   refU bf16 [b][h][c][w]  (u-contiguous, feeds cu staging)
//   refT bf16 [b][h][w][c]  (c-contiguous, feeds uc staging)
// ---------------------------------------------------------------------------
__global__ __launch_bounds__(256)
void cvt_kernel(const float* ref, short* refT, short* refU){
  __shared__ short T[128*130];
  int r = blockIdx.x, bb = blockIdx.y;
  int tid = threadIdx.x;
  const float* src = ref + (size_t)bb*CHW + (size_t)r*WW;
  short* uout = refU + (size_t)(bb*HH + r) * CC * WW;
  short* tout = refT + (size_t)(bb*HH + r) * WW * CC;
  #pragma unroll
  for (int k = 0; k < 16; k++){
    int q = tid + (k << 8);                 // 4096 float4 chunks
    int c = q >> 5, u0 = (q & 31) * 4;
    float4 v = *(const float4*)(src + (size_t)c*HW + u0);
    short h0 = f2bf(v.x), h1 = f2bf(v.y), h2 = f2bf(v.z), h3 = f2bf(v.w);
    s4v pk = {h0, h1, h2, h3};
    *(s4v*)&uout[(size_t)c*WW + u0] = pk;
    T[c*130 + u0 + 0] = h0; T[c*130 + u0 + 1] = h1;
    T[c*130 + u0 + 2] = h2; T[c*130 + u0 + 3] = h3;
  }
  __syncthreads();
  #pragma unroll
  for (int k = 0; k < 16; k++){
    int o = tid + (k << 8);
    int u = o >> 5, c0 = (o & 31) * 4;
    s4v pk = {T[(c0+0)*130 + u], T[(c0+1)*130 + u],
              T[(c0+2)*130 + u], T[(c0+3)*130 + u]};
    *(s4v*)&tout[(size_t)u*CC + c0] = pk;
  }
}

// ---------------------------------------------------------------------------
// kF round 5: 8-row bands, 8 waves (512 thr). Same per-wave structure as R4
// (each wave owns 1 output row, 2 barriers/iter, prefetch after 2nd barrier),
// but one 16-iter slide serves 8 rows: barriers/row 12->8.4, staging/output
// x2/3, per-thread stage work halved, 3 blocks/CU = 24 waves/CU (2x TLP).
// Conflict fixes: PP 32->40 (pa read was 8-way), paired case-interleaved
// g2/gt table (1 b64 gather, cases on distinct banks).
// LDS 47.1 KB: uc 8704 | fgs 34816 (A-overlay: cu 10240 + Pm 10240) |
//              cf 2048 | den/num/sa 1536
// ---------------------------------------------------------------------------
#define L_UC   0
#define L_FGS  8704
#define L_CU   8704
#define L_PM   18944
#define L_CF   43520
#define L_DEN  45568
#define L_NUM  46080
#define L_SA   46592
#define L_SZ   47104

template<int PRE>
__global__ __launch_bounds__(512, 6)
void kF(const float* f_in, const float* ref, const short* refT, const short* refU,
        const float* coef, float* f_out){
  __shared__ char smem[L_SZ];
  short* uc  = (short*)(smem + L_UC);    // [32 u][CP c]   (corr B-operand)
  short* cu  = (short*)(smem + L_CU);    // [128 c][UPITCH u] (corr_t B-operand, phase A)
  short* Pm  = (short*)(smem + L_PM);    // [8 wv][16 x][PP u]
  short* fgs = (short*)(smem + L_FGS);   // [128 px][CP c]  (fgrad, phase B)
  float* s_cf = (float*)(smem + L_CF);   // paired table + step/rw
  float* den = (float*)(smem + L_DEN);
  float* num = (float*)(smem + L_NUM);
  float* sa  = (float*)(smem + L_SA);

  int tid = threadIdx.x;
  int lane = tid & 63, wv = tid >> 6;          // 8 waves
  int quad = lane >> 4, col = lane & 15;

  // XCD-chunked bijective swizzle (512 blocks, 8 XCDs, chunk 64)
  int hwid = blockIdx.x + (blockIdx.y << 3) + (blockIdx.z << 7);
  int virt = ((hwid & 7) << 6) + (hwid >> 3);
  int bb = virt >> 7, y0 = ((virt >> 3) & 15) * 8, x0 = (virt & 7) * 16;

  int ub = x0 - 8;

  const float* fimg = f_in + (size_t)bb * CHW;
  const float* rimg = ref  + (size_t)bb * CHW;

  // ---- prefetch registers (PRE=1: bf16 chunks; PRE=0: raw fp32) ----
  s8v pT0, pU0;
  float4 pF0, pF1;

  auto loadT = [&](int r){
    if constexpr (PRE){
      const short* tb = refT + (size_t)(bb*HH + r) * WW * CC;
      int ua = ub + (tid >> 4);
      pT0 = (ua >= 0 && ua < WW)
            ? *(const s8v*)(tb + (size_t)ua*CC + ((tid & 15) << 3)) : (s8v)(short)0;
    } else {
      const float* rb = rimg + (size_t)r * WW;
      float4 z; z.x = z.y = z.z = z.w = 0.f;
      { int e = tid;       int ua = ub + (e & 7)*4;
        pF0 = (ua >= 0 && ua + 4 <= WW) ? *(const float4*)(rb + (size_t)(e >> 3)*HW + ua) : z; }
      { int e = tid + 512; int ua = ub + (e & 7)*4;
        pF1 = (ua >= 0 && ua + 4 <= WW) ? *(const float4*)(rb + (size_t)(e >> 3)*HW + ua) : z; }
    }
  };
  auto loadU = [&](int r){
    if constexpr (PRE){
      const short* ubp = refU + (size_t)(bb*HH + r) * CC * WW;
      int ua = ub + ((tid & 3) << 3);
      pU0 = (ua >= 0 && ua + 8 <= WW)
            ? *(const s8v*)(ubp + (size_t)(tid >> 2)*WW + ua) : (s8v)(short)0;
    }
  };
  auto writeRowA = [&](){
    if constexpr (PRE){
      *(s8v*)&uc[(tid >> 4)*CP + ((tid & 15) << 3)] = pT0;
      *(s8v*)&cu[(tid >> 2)*UPITCH + ((tid & 3) << 3)] = pU0;
    } else {
      float4 vv[2] = {pF0, pF1};
      #pragma unroll
      for (int k = 0; k < 2; k++){
        int e4 = tid + (k << 9);
        int u4 = (e4 & 7) * 4, c = e4 >> 3;
        short h0 = f2bf(vv[k].x), h1 = f2bf(vv[k].y),
              h2 = f2bf(vv[k].z), h3 = f2bf(vv[k].w);
        uc[(u4+0)*CP + c] = h0; uc[(u4+1)*CP + c] = h1;
        uc[(u4+2)*CP + c] = h2; uc[(u4+3)*CP + c] = h3;
        s4v pk = {h0, h1, h2, h3};
        *(s4v*)&cu[c*UPITCH + u4] = pk;
      }
    }
  };
  auto writeRowB = [&](){
    if constexpr (PRE){
      *(s8v*)&uc[(tid >> 4)*CP + ((tid & 15) << 3)] = pT0;
    } else {
      float4 vv[2] = {pF0, pF1};
      #pragma unroll
      for (int k = 0; k < 2; k++){
        int e4 = tid + (k << 9);
        int u4 = (e4 & 7) * 4, c = e4 >> 3;
        uc[(u4+0)*CP + c] = f2bf(vv[k].x); uc[(u4+1)*CP + c] = f2bf(vv[k].y);
        uc[(u4+2)*CP + c] = f2bf(vv[k].z); uc[(u4+3)*CP + c] = f2bf(vv[k].w);
      }
    }
  };

  // prologue: loads for rr=0 (row y0-4), in flight under coef copy + A-frag build
  if (y0 - 4 >= 0){ loadT(y0 - 4); loadU(y0 - 4); }

  if (tid < 512) s_cf[tid] = coef[tid];

  // ---- A-frags (f at row y0+wv, hi/lo split) straight from global ----
  int fy = y0 + wv;
  s8v a_hi[4], a_lo[4];
  #pragma unroll
  for (int kc = 0; kc < 4; kc++){
    short th[8], tl[8];
    #pragma unroll
    for (int j = 0; j < 8; j++){
      int c = kc*32 + quad*8 + j;
      float v = fimg[(size_t)c * HW + fy * WW + x0 + col];
      short h = f2bf(v);
      th[j] = h; tl[j] = f2bf(v - bf2f(h));
    }
    a_hi[kc] = *(const s8v*)th;
    a_lo[kc] = *(const s8v*)tl;
  }

  f4v D[8];
  #pragma unroll
  for (int i = 0; i < 8; i++) D[i] = (f4v)0.f;

  // sign FIFO: 9 x 16-bit packs in 3 u64 (push A, pop B, same order)
  unsigned long long f0 = 0ull, f1 = 0ull, f2 = 0ull;

  // =================== phase A: corr1 -> P -> corr_t ===================
  for (int rr = 0; rr < 16; rr++){
    int r = y0 + rr - 4;
    bool rv = (r >= 0) && (r < HH);
    __syncthreads();
    if (rv) writeRowA();
    __syncthreads();
    // issue next row's loads NOW: the vmcnt(0)-drain at the next barrier
    // is then covered by the compute below
    if (rr < 15){
      int rn = r + 1;
      if (rn >= 0 && rn < HH){ loadT(rn); loadU(rn); }
    }
    int dy = rr - wv;
    if (dy >= 0 && dy <= 8){
      unsigned pack = 0u;
      if (rv){
        // corr1: C[x,u] = sum_c (f_hi+f_lo)[x,c] * ref[c,u]
        f4v C0 = (f4v)0.f, C1 = (f4v)0.f;
        #pragma unroll
        for (int kc = 0; kc < 4; kc++){
          s8v b0 = *(const s8v*)&uc[col*CP      + kc*32 + quad*8];
          s8v b1 = *(const s8v*)&uc[(16+col)*CP + kc*32 + quad*8];
          C0 = __builtin_amdgcn_mfma_f32_16x16x32_bf16(a_hi[kc], b0, C0, 0,0,0);
          C0 = __builtin_amdgcn_mfma_f32_16x16x32_bf16(a_lo[kc], b0, C0, 0,0,0);
          C1 = __builtin_amdgcn_mfma_f32_16x16x32_bf16(a_hi[kc], b1, C1, 0,0,0);
          C1 = __builtin_amdgcn_mfma_f32_16x16x32_bf16(a_lo[kc], b1, C1, 0,0,0);
        }
        // scores -> sign pack (regs) + mapped -> P[x,u]
        #pragma unroll
        for (int nt = 0; nt < 2; nt++){
          f4v Cv = nt ? C1 : C0;
          #pragma unroll
          for (int reg = 0; reg < 4; reg++){
            int x  = quad*4 + reg;            // C/D row = (lane>>4)*4 + reg
            int up = nt*16 + col;             // C/D col = lane&15 (+tile)
            int dxm = up - x - 4;
            float m = 0.f;
            if ((unsigned)dxm <= 8u){
              float s = Cv[reg];
              int d = dy*9 + dxm;
              unsigned pos = (s > 0.f) ? 1u : 0u;
              unsigned neg = (s < 0.f) ? 1u : 0u;
              int cse = pos ? 0 : (neg ? 1 : 2);
              float2 gg = *(const float2*)&s_cf[(d*3 + cse)*2];
              m = fmaf(gg.x, s, -gg.y);
              pack |= (pos | (neg << 1)) << ((nt*4 + reg) * 2);
            }
            Pm[(wv*16 + x)*PP + up] = f2bf(m);
          }
        }
        // wave-local LDS handoff (keep global prefetch in flight)
        asm volatile("s_waitcnt lgkmcnt(0)" ::: "memory");
        __builtin_amdgcn_sched_barrier(0);
        // corr_t: D[x,c] += sum_u P[x,u] * ref[u,c]
        s8v pa = *(const s8v*)&Pm[(wv*16 + col)*PP + quad*8];
        #pragma unroll
        for (int ct = 0; ct < 8; ct++){
          s8v bc = *(const s8v*)&cu[(ct*16 + col)*UPITCH + quad*8];
          D[ct] = __builtin_amdgcn_mfma_f32_16x16x32_bf16(pa, bc, D[ct], 0,0,0);
        }
      }
      // FIFO push (always when dy in window, so A/B stay aligned)
      f0 = (f0 >> 16) | (f1 << 48);
      f1 = (f1 >> 16) | (f2 << 48);
      f2 = (f2 >> 16) | ((unsigned long long)pack << 48);
    }
  }

  // phase-B prologue loads fly under the epilogue work
  if (y0 - 4 >= 0) loadT(y0 - 4);

  // ---- epilogue-1: fgs = bf16(D + rw*f) (overlays cu+Pm), then num ----
  float rw = s_cf[501];
  __syncthreads();
  #pragma unroll
  for (int ct = 0; ct < 8; ct++){
    #pragma unroll
    for (int reg = 0; reg < 4; reg++){
      int x = quad*4 + reg, c = ct*16 + col;
      float fv = fimg[(size_t)c * HW + fy * WW + x0 + x];
      fgs[(wv*16 + x)*CP + c] = f2bf(D[ct][reg] + rw * fv);
    }
  }
  __syncthreads();
  {  // num: 4 threads per px row (128 px, 512 threads)
    int px = tid >> 2, k4 = (tid & 3) * 4;
    float s = 0.f;
    #pragma unroll
    for (int j = 0; j < 4; j++){
      s8v v = *(const s8v*)&fgs[px*CP + (k4 + j)*8];
      #pragma unroll
      for (int jj = 0; jj < 8; jj++){ float f = bf2f(v[jj]); s += f*f; }
    }
    s += __shfl_xor(s, 1);
    s += __shfl_xor(s, 2);
    if ((tid & 3) == 0) num[px] = s;
  }

  // =================== phase B: corr(fgrad) -> den -> update ===================
  s8v ga_[4];
  #pragma unroll
  for (int kc = 0; kc < 4; kc++)
    ga_[kc] = *(const s8v*)&fgs[(wv*16 + col)*CP + kc*32 + quad*8];

  float dacc[4] = {0.f, 0.f, 0.f, 0.f};    // per-thread den partials (by reg)

  for (int rr = 0; rr < 16; rr++){
    int r = y0 + rr - 4;
    bool rv = (r >= 0) && (r < HH);
    __syncthreads();
    if (rv) writeRowB();
    __syncthreads();
    if (rr < 15){
      int rn = r + 1;
      if (rn >= 0 && rn < HH) loadT(rn);
    }
    int dy = rr - wv;
    if (dy >= 0 && dy <= 8){
      // FIFO pop (mirrors phase-A push order)
      unsigned pack = (unsigned)(f0 >> 48) & 0xFFFFu;
      f0 = (f0 >> 16) | (f1 << 48);
      f1 = (f1 >> 16) | (f2 << 48);
      f2 >>= 16;
      if (rv){
        f4v C0 = (f4v)0.f, C1 = (f4v)0.f;
        #pragma unroll
        for (int kc = 0; kc < 4; kc++){
          s8v b0 = *(const s8v*)&uc[col*CP      + kc*32 + quad*8];
          s8v b1 = *(const s8v*)&uc[(16+col)*CP + kc*32 + quad*8];
          C0 = __builtin_amdgcn_mfma_f32_16x16x32_bf16(ga_[kc], b0, C0, 0,0,0);
          C1 = __builtin_amdgcn_mfma_f32_16x16x32_bf16(ga_[kc], b1, C1, 0,0,0);
        }
        #pragma unroll
        for (int nt = 0; nt < 2; nt++){
          f4v Cv = nt ? C1 : C0;
          #pragma unroll
          for (int reg = 0; reg < 4; reg++){
            int x  = quad*4 + reg;
            int up = nt*16 + col;
            int dxm = up - x - 4;
            if ((unsigned)dxm <= 8u){
              int d = dy*9 + dxm;
              unsigned b2 = pack >> ((nt*4 + reg) * 2);
              int cse = (b2 & 1u) ? 0 : ((b2 & 2u) ? 1 : 2);
              float g2 = s_cf[(d*3 + cse)*2];
              float t  = Cv[reg];
              dacc[reg] = fmaf(g2 * t, t, dacc[reg]);
            }
          }
        }
      }
    }
  }

  // den: reduce partials across the 16 col-lanes of each quad (no atomics)
  #pragma unroll
  for (int reg = 0; reg < 4; reg++){
    float v = dacc[reg];
    v += __shfl_xor(v, 1);
    v += __shfl_xor(v, 2);
    v += __shfl_xor(v, 4);
    v += __shfl_xor(v, 8);
    if (col == 0) den[wv*16 + quad*4 + reg] = v;
  }

  __syncthreads();
  if (tid < 128){
    float step = s_cf[500];
    float alpha = num[tid] / fmaxf(den[tid] + rw*num[tid], 1e-8f);
    sa[tid] = step * alpha;
  }
  __syncthreads();

  // ---- update: f_out = f - step*alpha*fgrad (coalesced) ----
  float* oimg = f_out + (size_t)bb * CHW;
  for (int e = tid; e < 16384; e += 512){
    int x = e & 15, y = (e >> 4) & 7, c = e >> 7;
    size_t gi = (size_t)c * HW + (y0 + y) * WW + x0 + x;
    float v = fimg[gi] - sa[y*16 + x] * bf2f(fgs[(y*16 + x)*CP + c]);
    oimg[gi] = v;
  }
}

// ---------------------------------------------------------------------------
extern "C" void kernel_launch(void* const* d_in, const int* in_sizes, int n_in,
                              void* d_out, int out_size, void* d_ws, size_t ws_size,
                              hipStream_t stream) {
  const float* filter_map = (const float*)d_in[0];
  const float* ref        = (const float*)d_in[1];
  const float* label_w    = (const float*)d_in[2];
  const float* spatial_w  = (const float*)d_in[3];
  const float* mask_w     = (const float*)d_in[4];
  const float* lsl        = (const float*)d_in[5];
  const float* freg       = (const float*)d_in[6];

  float* coef = (float*)d_ws;      // coef tables (64 KB region reserved)
  float* fbuf = (float*)d_out;     // evolving filter lives in d_out (fp32)

  // bf16 pre-transposed ref copies in workspace (guarded by ws_size)
  short* refT = (short*)((char*)d_ws + 65536);
  short* refU = refT + (size_t)BB * CHW;
  size_t need = 65536 + 2 * (size_t)BB * CHW * sizeof(short);
  bool pre = (ws_size >= need);

  coef_kernel<<<dim3(1), dim3(128), 0, stream>>>(label_w, spatial_w, mask_w, lsl, freg, coef);
  if (pre)
    cvt_kernel<<<dim3(HH, BB), dim3(256), 0, stream>>>(ref, refT, refU);

  dim3 grid(8, 16, BB);   // 16-col x-tiles, 8-row y-bands, batch
  for (int it = 0; it < 3; it++){
    const float* fsrc = (it == 0) ? filter_map : (const float*)fbuf;
    if (pre) kF<1><<<grid, 512, 0, stream>>>(fsrc, ref, refT, refU, coef, fbuf);
    else     kF<0><<<grid, 512, 0, stream>>>(fsrc, ref, refT, refU, coef, fbuf);
  }
}

// Round 6
// 547.317 us; speedup vs baseline: 1.0726x; 1.0726x over previous
//
#include <hip/hip_runtime.h>

#define BB 4
#define CC 128
#define HH 128
#define WW 128
#define HW (HH*WW)
#define CHW (CC*HW)
#define ND 81
#define CP 136      // c-stride (shorts) for uc/fgs: 272 B rows -> 16B aligned, 2-way-free b128 reads
#define UPITCH 40   // u-stride (shorts) for cu: 80 B rows = 5x16B -> b128-aligned, 2-way-free
#define PP 40       // P tile u stride (shorts): 80 B rows -> pa b128 read 2-way (was 8-way at 32)

typedef short s8v __attribute__((ext_vector_type(8)));   // 8 bf16 MFMA A/B frag
typedef short s4v __attribute__((ext_vector_type(4)));
typedef float f4v __attribute__((ext_vector_type(4)));   // MFMA C/D frag

__device__ __forceinline__ short f2bf(float x){          // RNE float->bf16 bits
  unsigned u = __float_as_uint(x);
  unsigned r = (u + 0x7FFFu + ((u >> 16) & 1u)) >> 16;
  return (short)r;
}
__device__ __forceinline__ float bf2f(short s){
  return __uint_as_float(((unsigned)(unsigned short)s) << 16);
}

// ---------------------------------------------------------------------------
// coef: paired sign-case tables, interleaved so the 3 cases hit different
// banks and one b64 gather fetches both values:
//   coef[(d*3+case)*2 + 0] = g2 = ga^2,  [..+1] = gt = ga*vp*t
//   ga = vp (s>0), vp*wm (s<0), vp*ah (s==0)    [a_lo+a_hi=1, a_hi-a_lo=wm]
// mapped m = g2*s - gt exactly; den elem = g2*t*t.
// [500]=step_length, [501]=reg_weight
// ---------------------------------------------------------------------------
__global__ void coef_kernel(const float* lw, const float* sw, const float* mw,
                            const float* lsl, const float* fr, float* coef){
  int d = threadIdx.x;
  if (d < ND){
    float dy = (float)(d / 9) - 4.0f;
    float dx = (float)(d % 9) - 4.0f;
    float dist = sqrtf(dy*dy + dx*dx) * 2.0f;
    float t = 0.f, v = 0.f, m = 0.f;
    for (int k = 0; k < 10; k++){
      float bd = dist - (float)k;
      float val = (k == 9) ? fminf(fmaxf(bd + 1.0f, 0.f), 1.f)
                           : fmaxf(1.0f - fabsf(bd), 0.f);
      t += val * lw[k]; v += val * sw[k]; m += val * mw[k];
    }
    float wm = 1.f / (1.f + expf(-m));
    float ah = (1.f + wm) * 0.5f;
    float gp = v, gn = v * wm, gz = v * ah;   // ga per sign case
    float vt = v * t;
    coef[(d*3+0)*2+0] = gp * gp;  coef[(d*3+0)*2+1] = gp * vt;
    coef[(d*3+1)*2+0] = gn * gn;  coef[(d*3+1)*2+1] = gn * vt;
    coef[(d*3+2)*2+0] = gz * gz;  coef[(d*3+2)*2+1] = gz * vt;
  }
  if (threadIdx.x == 0){
    coef[500] = expf(lsl[0]);
    float f = fr[0];
    coef[501] = fmaxf(f*f, 1e-10f) / (float)(CC*CC);
  }
}

// ---------------------------------------------------------------------------
// one-time convert: ref fp32 [b][c][h][w] ->
//   refU bf16 [b][h][c][w]  (u-contiguous, feeds cu staging)
//   refT bf16 [b][h][w][c]  (c-contiguous, feeds uc staging)
// ---------------------------------------------------------------------------
__global__ __launch_bounds__(256)
void cvt_kernel(const float* ref, short* refT, short* refU){
  __shared__ short T[128*130];
  int r = blockIdx.x, bb = blockIdx.y;
  int tid = threadIdx.x;
  const float* src = ref + (size_t)bb*CHW + (size_t)r*WW;
  short* uout = refU + (size_t)(bb*HH + r) * CC * WW;
  short* tout = refT + (size_t)(bb*HH + r) * WW * CC;
  #pragma unroll
  for (int k = 0; k < 16; k++){
    int q = tid + (k << 8);                 // 4096 float4 chunks
    int c = q >> 5, u0 = (q & 31) * 4;
    float4 v = *(const float4*)(src + (size_t)c*HW + u0);
    short h0 = f2bf(v.x), h1 = f2bf(v.y), h2 = f2bf(v.z), h3 = f2bf(v.w);
    s4v pk = {h0, h1, h2, h3};
    *(s4v*)&uout[(size_t)c*WW + u0] = pk;
    T[c*130 + u0 + 0] = h0; T[c*130 + u0 + 1] = h1;
    T[c*130 + u0 + 2] = h2; T[c*130 + u0 + 3] = h3;
  }
  __syncthreads();
  #pragma unroll
  for (int k = 0; k < 16; k++){
    int o = tid + (k << 8);
    int u = o >> 5, c0 = (o & 31) * 4;
    s4v pk = {T[(c0+0)*130 + u], T[(c0+1)*130 + u],
              T[(c0+2)*130 + u], T[(c0+3)*130 + u]};
    *(s4v*)&tout[(size_t)u*CC + c0] = pk;
  }
}

// ---------------------------------------------------------------------------
// kF round 6 = R4's proven skeleton (256 thr, 4-row bands, 64 VGPR, 2
// barriers/iter, prefetch after 2nd barrier) + isolated conflict fixes from
// R5 (PP=40 pa-read, paired bank-spread g2/gt table) + 5 blocks/CU
// (LDS 28.9 KB fits 5; launch_bounds(256,5) budget 102 VGPR >= the 64 used,
// so no R5-style spill risk). R5's 8-wave design spilled D[8] to scratch
// (VGPR_Count 40, WRITE_SIZE 330 MB) -- reverted.
// ---------------------------------------------------------------------------
#define L_UC   0            // 8704
#define L_FGS  8704         // 17408 (phase-A overlay: cu 10240 + Pm 5120)
#define L_CU   8704
#define L_PM   18944
#define L_CF   26112        // 512 floats = 2048
#define L_DEN  28160
#define L_NUM  28416
#define L_SA   28672
#define L_SZ   28928

template<int PRE>
__global__ __launch_bounds__(256, 5)
void kF(const float* f_in, const float* ref, const short* refT, const short* refU,
        const float* coef, float* f_out){
  __shared__ char smem[L_SZ];
  short* uc  = (short*)(smem + L_UC);    // [32 u][CP c]   (corr B-operand)
  short* cu  = (short*)(smem + L_CU);    // [128 c][UPITCH u] (corr_t B-operand, phase A)
  short* Pm  = (short*)(smem + L_PM);    // [4 wv][16 x][PP u]
  short* fgs = (short*)(smem + L_FGS);   // [64 px][CP c]  (fgrad, phase B)
  float* s_cf = (float*)(smem + L_CF);   // paired g2/gt table + step/rw
  float* den = (float*)(smem + L_DEN);
  float* num = (float*)(smem + L_NUM);
  float* sa  = (float*)(smem + L_SA);

  int tid = threadIdx.x;
  int lane = tid & 63, wv = tid >> 6;
  int quad = lane >> 4, col = lane & 15;

  // XCD-chunked bijective swizzle (1024 blocks, 8 XCDs)
  int hwid = blockIdx.x + (blockIdx.y << 3) + (blockIdx.z << 8);
  int virt = ((hwid & 7) << 7) + (hwid >> 3);
  int bb = virt >> 8, y0 = ((virt >> 3) & 31) * 4, x0 = (virt & 7) * 16;

  int ub = x0 - 8;

  const float* fimg = f_in + (size_t)bb * CHW;
  const float* rimg = ref  + (size_t)bb * CHW;

  // ---- prefetch registers (PRE=1: bf16 chunks; PRE=0: raw fp32) ----
  s8v pT0, pT1, pU0, pU1;
  float4 pF0, pF1, pF2, pF3;

  auto loadT = [&](int r){
    if constexpr (PRE){
      const short* tb = refT + (size_t)(bb*HH + r) * WW * CC;
      { int e = tid;       int ua = ub + (e >> 4);
        pT0 = (ua >= 0 && ua < WW)
              ? *(const s8v*)(tb + (size_t)ua*CC + ((e & 15) << 3)) : (s8v)(short)0; }
      { int e = tid + 256; int ua = ub + (e >> 4);
        pT1 = (ua >= 0 && ua < WW)
              ? *(const s8v*)(tb + (size_t)ua*CC + ((e & 15) << 3)) : (s8v)(short)0; }
    } else {
      const float* rb = rimg + (size_t)r * WW;
      float4 z; z.x = z.y = z.z = z.w = 0.f;
      { int e = tid;       int ua = ub + (e & 7)*4;
        pF0 = (ua >= 0 && ua + 4 <= WW) ? *(const float4*)(rb + (size_t)(e >> 3)*HW + ua) : z; }
      { int e = tid + 256; int ua = ub + (e & 7)*4;
        pF1 = (ua >= 0 && ua + 4 <= WW) ? *(const float4*)(rb + (size_t)(e >> 3)*HW + ua) : z; }
      { int e = tid + 512; int ua = ub + (e & 7)*4;
        pF2 = (ua >= 0 && ua + 4 <= WW) ? *(const float4*)(rb + (size_t)(e >> 3)*HW + ua) : z; }
      { int e = tid + 768; int ua = ub + (e & 7)*4;
        pF3 = (ua >= 0 && ua + 4 <= WW) ? *(const float4*)(rb + (size_t)(e >> 3)*HW + ua) : z; }
    }
  };
  auto loadU = [&](int r){
    if constexpr (PRE){
      const short* ubp = refU + (size_t)(bb*HH + r) * CC * WW;
      { int e = tid;       int ua = ub + ((e & 3) << 3);
        pU0 = (ua >= 0 && ua + 8 <= WW)
              ? *(const s8v*)(ubp + (size_t)(e >> 2)*WW + ua) : (s8v)(short)0; }
      { int e = tid + 256; int ua = ub + ((e & 3) << 3);
        pU1 = (ua >= 0 && ua + 8 <= WW)
              ? *(const s8v*)(ubp + (size_t)(e >> 2)*WW + ua) : (s8v)(short)0; }
    }
  };
  auto writeRowA = [&](){
    if constexpr (PRE){
      { int e = tid;       *(s8v*)&uc[(e >> 4)*CP + ((e & 15) << 3)] = pT0; }
      { int e = tid + 256; *(s8v*)&uc[(e >> 4)*CP + ((e & 15) << 3)] = pT1; }
      { int e = tid;       *(s8v*)&cu[(e >> 2)*UPITCH + ((e & 3) << 3)] = pU0; }
      { int e = tid + 256; *(s8v*)&cu[(e >> 2)*UPITCH + ((e & 3) << 3)] = pU1; }
    } else {
      float4 vv[4] = {pF0, pF1, pF2, pF3};
      #pragma unroll
      for (int k = 0; k < 4; k++){
        int e4 = tid + (k << 8);
        int u4 = (e4 & 7) * 4, c = e4 >> 3;
        short h0 = f2bf(vv[k].x), h1 = f2bf(vv[k].y),
              h2 = f2bf(vv[k].z), h3 = f2bf(vv[k].w);
        uc[(u4+0)*CP + c] = h0; uc[(u4+1)*CP + c] = h1;
        uc[(u4+2)*CP + c] = h2; uc[(u4+3)*CP + c] = h3;
        s4v pk = {h0, h1, h2, h3};
        *(s4v*)&cu[c*UPITCH + u4] = pk;
      }
    }
  };
  auto writeRowB = [&](){
    if constexpr (PRE){
      { int e = tid;       *(s8v*)&uc[(e >> 4)*CP + ((e & 15) << 3)] = pT0; }
      { int e = tid + 256; *(s8v*)&uc[(e >> 4)*CP + ((e & 15) << 3)] = pT1; }
    } else {
      float4 vv[4] = {pF0, pF1, pF2, pF3};
      #pragma unroll
      for (int k = 0; k < 4; k++){
        int e4 = tid + (k << 8);
        int u4 = (e4 & 7) * 4, c = e4 >> 3;
        uc[(u4+0)*CP + c] = f2bf(vv[k].x); uc[(u4+1)*CP + c] = f2bf(vv[k].y);
        uc[(u4+2)*CP + c] = f2bf(vv[k].z); uc[(u4+3)*CP + c] = f2bf(vv[k].w);
      }
    }
  };

  // prologue: loads for rr=0 (row y0-4), in flight under coef copy + A-frag build
  if (y0 - 4 >= 0){ loadT(y0 - 4); loadU(y0 - 4); }

  for (int e = tid; e < 512; e += 256) s_cf[e] = coef[e];

  // ---- A-frags (f at row y0+wv, hi/lo split) straight from global ----
  int fy = y0 + wv;
  s8v a_hi[4], a_lo[4];
  #pragma unroll
  for (int kc = 0; kc < 4; kc++){
    short th[8], tl[8];
    #pragma unroll
    for (int j = 0; j < 8; j++){
      int c = kc*32 + quad*8 + j;
      float v = fimg[(size_t)c * HW + fy * WW + x0 + col];
      short h = f2bf(v);
      th[j] = h; tl[j] = f2bf(v - bf2f(h));
    }
    a_hi[kc] = *(const s8v*)th;
    a_lo[kc] = *(const s8v*)tl;
  }

  f4v D[8];
  #pragma unroll
  for (int i = 0; i < 8; i++) D[i] = (f4v)0.f;

  // sign FIFO: 9 x 16-bit packs in 3 u64 (push A, pop B, same order)
  unsigned long long f0 = 0ull, f1 = 0ull, f2 = 0ull;

  // =================== phase A: corr1 -> P -> corr_t ===================
  for (int rr = 0; rr < 12; rr++){
    int r = y0 + rr - 4;
    bool rv = (r >= 0) && (r < HH);
    __syncthreads();
    if (rv) writeRowA();
    __syncthreads();
    // issue next row's loads NOW: the vmcnt(0)-drain at the next barrier
    // is then covered by the compute below
    if (rr < 11){
      int rn = r + 1;
      if (rn >= 0 && rn < HH){ loadT(rn); loadU(rn); }
    }
    int dy = rr - wv;
    if (dy >= 0 && dy <= 8){
      unsigned pack = 0u;
      if (rv){
        // corr1: C[x,u] = sum_c (f_hi+f_lo)[x,c] * ref[c,u]
        f4v C0 = (f4v)0.f, C1 = (f4v)0.f;
        #pragma unroll
        for (int kc = 0; kc < 4; kc++){
          s8v b0 = *(const s8v*)&uc[col*CP      + kc*32 + quad*8];
          s8v b1 = *(const s8v*)&uc[(16+col)*CP + kc*32 + quad*8];
          C0 = __builtin_amdgcn_mfma_f32_16x16x32_bf16(a_hi[kc], b0, C0, 0,0,0);
          C0 = __builtin_amdgcn_mfma_f32_16x16x32_bf16(a_lo[kc], b0, C0, 0,0,0);
          C1 = __builtin_amdgcn_mfma_f32_16x16x32_bf16(a_hi[kc], b1, C1, 0,0,0);
          C1 = __builtin_amdgcn_mfma_f32_16x16x32_bf16(a_lo[kc], b1, C1, 0,0,0);
        }
        // scores -> sign pack (regs) + mapped -> P[x,u]
        #pragma unroll
        for (int nt = 0; nt < 2; nt++){
          f4v Cv = nt ? C1 : C0;
          #pragma unroll
          for (int reg = 0; reg < 4; reg++){
            int x  = quad*4 + reg;            // C/D row = (lane>>4)*4 + reg
            int up = nt*16 + col;             // C/D col = lane&15 (+tile)
            int dxm = up - x - 4;
            float m = 0.f;
            if ((unsigned)dxm <= 8u){
              float s = Cv[reg];
              int d = dy*9 + dxm;
              unsigned pos = (s > 0.f) ? 1u : 0u;
              unsigned neg = (s < 0.f) ? 1u : 0u;
              int cse = pos ? 0 : (neg ? 1 : 2);
              float2 gg = *(const float2*)&s_cf[(d*3 + cse)*2];
              m = fmaf(gg.x, s, -gg.y);
              pack |= (pos | (neg << 1)) << ((nt*4 + reg) * 2);
            }
            Pm[(wv*16 + x)*PP + up] = f2bf(m);
          }
        }
        // wave-local LDS handoff (keep global prefetch in flight)
        asm volatile("s_waitcnt lgkmcnt(0)" ::: "memory");
        __builtin_amdgcn_sched_barrier(0);
        // corr_t: D[x,c] += sum_u P[x,u] * ref[u,c]
        s8v pa = *(const s8v*)&Pm[(wv*16 + col)*PP + quad*8];
        #pragma unroll
        for (int ct = 0; ct < 8; ct++){
          s8v bc = *(const s8v*)&cu[(ct*16 + col)*UPITCH + quad*8];
          D[ct] = __builtin_amdgcn_mfma_f32_16x16x32_bf16(pa, bc, D[ct], 0,0,0);
        }
      }
      // FIFO push (always when dy in window, so A/B stay aligned)
      f0 = (f0 >> 16) | (f1 << 48);
      f1 = (f1 >> 16) | (f2 << 48);
      f2 = (f2 >> 16) | ((unsigned long long)pack << 48);
    }
  }

  // phase-B prologue loads fly under the epilogue work
  if (y0 - 4 >= 0) loadT(y0 - 4);

  // ---- epilogue-1: fgs = bf16(D + rw*f) (overlays cu+Pm), then num ----
  float rw = s_cf[501];
  __syncthreads();
  #pragma unroll
  for (int ct = 0; ct < 8; ct++){
    #pragma unroll
    for (int reg = 0; reg < 4; reg++){
      int x = quad*4 + reg, c = ct*16 + col;
      float fv = fimg[(size_t)c * HW + fy * WW + x0 + x];
      fgs[(wv*16 + x)*CP + c] = f2bf(D[ct][reg] + rw * fv);
    }
  }
  __syncthreads();
  if (tid < 64){
    float s = 0.f;
    #pragma unroll
    for (int kc = 0; kc < 16; kc++){
      s8v v = *(const s8v*)&fgs[tid*CP + kc*8];
      #pragma unroll
      for (int j = 0; j < 8; j++){ float f = bf2f(v[j]); s += f*f; }
    }
    num[tid] = s;
  }

  // =================== phase B: corr(fgrad) -> den -> update ===================
  s8v ga_[4];
  #pragma unroll
  for (int kc = 0; kc < 4; kc++)
    ga_[kc] = *(const s8v*)&fgs[(wv*16 + col)*CP + kc*32 + quad*8];

  float dacc[4] = {0.f, 0.f, 0.f, 0.f};    // per-thread den partials (by reg)

  for (int rr = 0; rr < 12; rr++){
    int r = y0 + rr - 4;
    bool rv = (r >= 0) && (r < HH);
    __syncthreads();
    if (rv) writeRowB();
    __syncthreads();
    if (rr < 11){
      int rn = r + 1;
      if (rn >= 0 && rn < HH) loadT(rn);
    }
    int dy = rr - wv;
    if (dy >= 0 && dy <= 8){
      // FIFO pop (mirrors phase-A push order)
      unsigned pack = (unsigned)(f0 >> 48) & 0xFFFFu;
      f0 = (f0 >> 16) | (f1 << 48);
      f1 = (f1 >> 16) | (f2 << 48);
      f2 >>= 16;
      if (rv){
        f4v C0 = (f4v)0.f, C1 = (f4v)0.f;
        #pragma unroll
        for (int kc = 0; kc < 4; kc++){
          s8v b0 = *(const s8v*)&uc[col*CP      + kc*32 + quad*8];
          s8v b1 = *(const s8v*)&uc[(16+col)*CP + kc*32 + quad*8];
          C0 = __builtin_amdgcn_mfma_f32_16x16x32_bf16(ga_[kc], b0, C0, 0,0,0);
          C1 = __builtin_amdgcn_mfma_f32_16x16x32_bf16(ga_[kc], b1, C1, 0,0,0);
        }
        #pragma unroll
        for (int nt = 0; nt < 2; nt++){
          f4v Cv = nt ? C1 : C0;
          #pragma unroll
          for (int reg = 0; reg < 4; reg++){
            int x  = quad*4 + reg;
            int up = nt*16 + col;
            int dxm = up - x - 4;
            if ((unsigned)dxm <= 8u){
              int d = dy*9 + dxm;
              unsigned b2 = pack >> ((nt*4 + reg) * 2);
              int cse = (b2 & 1u) ? 0 : ((b2 & 2u) ? 1 : 2);
              float g2 = s_cf[(d*3 + cse)*2];
              float t  = Cv[reg];
              dacc[reg] = fmaf(g2 * t, t, dacc[reg]);
            }
          }
        }
      }
    }
  }

  // den: reduce partials across the 16 col-lanes of each quad (no atomics)
  #pragma unroll
  for (int reg = 0; reg < 4; reg++){
    float v = dacc[reg];
    v += __shfl_xor(v, 1);
    v += __shfl_xor(v, 2);
    v += __shfl_xor(v, 4);
    v += __shfl_xor(v, 8);
    if (col == 0) den[wv*16 + quad*4 + reg] = v;
  }

  __syncthreads();
  if (tid < 64){
    float step = s_cf[500];
    float alpha = num[tid] / fmaxf(den[tid] + rw*num[tid], 1e-8f);
    sa[tid] = step * alpha;
  }
  __syncthreads();

  // ---- update: f_out = f - step*alpha*fgrad (coalesced) ----
  float* oimg = f_out + (size_t)bb * CHW;
  for (int e = tid; e < 8192; e += 256){
    int x = e & 15, y = (e >> 4) & 3, c = e >> 6;
    size_t gi = (size_t)c * HW + (y0 + y) * WW + x0 + x;
    float v = fimg[gi] - sa[y*16 + x] * bf2f(fgs[(y*16 + x)*CP + c]);
    oimg[gi] = v;
  }
}

// ---------------------------------------------------------------------------
extern "C" void kernel_launch(void* const* d_in, const int* in_sizes, int n_in,
                              void* d_out, int out_size, void* d_ws, size_t ws_size,
                              hipStream_t stream) {
  const float* filter_map = (const float*)d_in[0];
  const float* ref        = (const float*)d_in[1];
  const float* label_w    = (const float*)d_in[2];
  const float* spatial_w  = (const float*)d_in[3];
  const float* mask_w     = (const float*)d_in[4];
  const float* lsl        = (const float*)d_in[5];
  const float* freg       = (const float*)d_in[6];

  float* coef = (float*)d_ws;      // coef tables (64 KB region reserved)
  float* fbuf = (float*)d_out;     // evolving filter lives in d_out (fp32)

  // bf16 pre-transposed ref copies in workspace (guarded by ws_size)
  short* refT = (short*)((char*)d_ws + 65536);
  short* refU = refT + (size_t)BB * CHW;
  size_t need = 65536 + 2 * (size_t)BB * CHW * sizeof(short);
  bool pre = (ws_size >= need);

  coef_kernel<<<dim3(1), dim3(128), 0, stream>>>(label_w, spatial_w, mask_w, lsl, freg, coef);
  if (pre)
    cvt_kernel<<<dim3(HH, BB), dim3(256), 0, stream>>>(ref, refT, refU);

  dim3 grid(8, 32, BB);   // 16-col x-tiles, 4-row y-bands, batch
  for (int it = 0; it < 3; it++){
    const float* fsrc = (it == 0) ? filter_map : (const float*)fbuf;
    if (pre) kF<1><<<grid, 256, 0, stream>>>(fsrc, ref, refT, refU, coef, fbuf);
    else     kF<0><<<grid, 256, 0, stream>>>(fsrc, ref, refT, refU, coef, fbuf);
  }
}

// Round 7
// 334.673 us; speedup vs baseline: 1.7541x; 1.6354x over previous
//
#include <hip/hip_runtime.h>

#define BB 4
#define CC 128
#define HH 128
#define WW 128
#define HW (HH*WW)
#define CHW (CC*HW)
#define ND 81
#define CP 136      // c-stride (shorts) for uc/fgs: 272 B rows -> 16B aligned, 2-way-free b128 reads
#define UPITCH 40   // u-stride (shorts) for cu: 80 B rows = 5x16B -> b128-aligned, 2-way-free
#define PP 40       // P tile u stride (shorts): 80 B rows -> pa b128 read 2-way (was 8-way at 32)

typedef short s8v __attribute__((ext_vector_type(8)));   // 8 bf16 MFMA A/B frag
typedef short s4v __attribute__((ext_vector_type(4)));
typedef float f4v __attribute__((ext_vector_type(4)));   // MFMA C/D frag

__device__ __forceinline__ short f2bf(float x){          // RNE float->bf16 bits
  unsigned u = __float_as_uint(x);
  unsigned r = (u + 0x7FFFu + ((u >> 16) & 1u)) >> 16;
  return (short)r;
}
__device__ __forceinline__ float bf2f(short s){
  return __uint_as_float(((unsigned)(unsigned short)s) << 16);
}

// ---------------------------------------------------------------------------
// coef: paired sign-case tables, interleaved so the 3 cases hit different
// banks and one b64 gather fetches both values:
//   coef[(d*3+case)*2 + 0] = g2 = ga^2,  [..+1] = gt = ga*vp*t
//   ga = vp (s>0), vp*wm (s<0), vp*ah (s==0)    [a_lo+a_hi=1, a_hi-a_lo=wm]
// mapped m = g2*s - gt exactly; den elem = g2*t*t.
// [500]=step_length, [501]=reg_weight
// ---------------------------------------------------------------------------
__global__ void coef_kernel(const float* lw, const float* sw, const float* mw,
                            const float* lsl, const float* fr, float* coef){
  int d = threadIdx.x;
  if (d < ND){
    float dy = (float)(d / 9) - 4.0f;
    float dx = (float)(d % 9) - 4.0f;
    float dist = sqrtf(dy*dy + dx*dx) * 2.0f;
    float t = 0.f, v = 0.f, m = 0.f;
    for (int k = 0; k < 10; k++){
      float bd = dist - (float)k;
      float val = (k == 9) ? fminf(fmaxf(bd + 1.0f, 0.f), 1.f)
                           : fmaxf(1.0f - fabsf(bd), 0.f);
      t += val * lw[k]; v += val * sw[k]; m += val * mw[k];
    }
    float wm = 1.f / (1.f + expf(-m));
    float ah = (1.f + wm) * 0.5f;
    float gp = v, gn = v * wm, gz = v * ah;   // ga per sign case
    float vt = v * t;
    coef[(d*3+0)*2+0] = gp * gp;  coef[(d*3+0)*2+1] = gp * vt;
    coef[(d*3+1)*2+0] = gn * gn;  coef[(d*3+1)*2+1] = gn * vt;
    coef[(d*3+2)*2+0] = gz * gz;  coef[(d*3+2)*2+1] = gz * vt;
  }
  if (threadIdx.x == 0){
    coef[500] = expf(lsl[0]);
    float f = fr[0];
    coef[501] = fmaxf(f*f, 1e-10f) / (float)(CC*CC);
  }
}

// ---------------------------------------------------------------------------
// one-time convert: ref fp32 [b][c][h][w] ->
//   refU bf16 [b][h][c][w]  (u-contiguous, feeds cu staging)
//   refT bf16 [b][h][w][c]  (c-contiguous, feeds uc staging)
// ---------------------------------------------------------------------------
__global__ __launch_bounds__(256)
void cvt_kernel(const float* ref, short* refT, short* refU){
  __shared__ short T[128*130];
  int r = blockIdx.x, bb = blockIdx.y;
  int tid = threadIdx.x;
  const float* src = ref + (size_t)bb*CHW + (size_t)r*WW;
  short* uout = refU + (size_t)(bb*HH + r) * CC * WW;
  short* tout = refT + (size_t)(bb*HH + r) * WW * CC;
  #pragma unroll
  for (int k = 0; k < 16; k++){
    int q = tid + (k << 8);                 // 4096 float4 chunks
    int c = q >> 5, u0 = (q & 31) * 4;
    float4 v = *(const float4*)(src + (size_t)c*HW + u0);
    short h0 = f2bf(v.x), h1 = f2bf(v.y), h2 = f2bf(v.z), h3 = f2bf(v.w);
    s4v pk = {h0, h1, h2, h3};
    *(s4v*)&uout[(size_t)c*WW + u0] = pk;
    T[c*130 + u0 + 0] = h0; T[c*130 + u0 + 1] = h1;
    T[c*130 + u0 + 2] = h2; T[c*130 + u0 + 3] = h3;
  }
  __syncthreads();
  #pragma unroll
  for (int k = 0; k < 16; k++){
    int o = tid + (k << 8);
    int u = o >> 5, c0 = (o & 31) * 4;
    s4v pk = {T[(c0+0)*130 + u], T[(c0+1)*130 + u],
              T[(c0+2)*130 + u], T[(c0+3)*130 + u]};
    *(s4v*)&tout[(size_t)u*CC + c0] = pk;
  }
}

// ---------------------------------------------------------------------------
// kF round 7 = R4's proven skeleton (256 thr, 4-row bands, 2 barriers/iter,
// prefetch after 2nd barrier) + PP=40 pa-read fix + paired bank-spread g2/gt
// table. launch_bounds back to (256,4): R6's (256,5) forced the allocator
// under the kernel's ~70-reg live set (gfx950 occupancy steps at 64/128/256
// VGPR, m69) -> 48 VGPR + 292 MB scratch spill. (256,4) gave exactly 64 VGPR
// with zero spill in R4; the 2nd arg is an allocator minimum, not an
// occupancy cap, so 5 blocks/CU (LDS-limited) remain possible.
// ---------------------------------------------------------------------------
#define L_UC   0            // 8704
#define L_FGS  8704         // 17408 (phase-A overlay: cu 10240 + Pm 5120)
#define L_CU   8704
#define L_PM   18944
#define L_CF   26112        // 512 floats = 2048
#define L_DEN  28160
#define L_NUM  28416
#define L_SA   28672
#define L_SZ   28928

template<int PRE>
__global__ __launch_bounds__(256, 4)
void kF(const float* f_in, const float* ref, const short* refT, const short* refU,
        const float* coef, float* f_out){
  __shared__ char smem[L_SZ];
  short* uc  = (short*)(smem + L_UC);    // [32 u][CP c]   (corr B-operand)
  short* cu  = (short*)(smem + L_CU);    // [128 c][UPITCH u] (corr_t B-operand, phase A)
  short* Pm  = (short*)(smem + L_PM);    // [4 wv][16 x][PP u]
  short* fgs = (short*)(smem + L_FGS);   // [64 px][CP c]  (fgrad, phase B)
  float* s_cf = (float*)(smem + L_CF);   // paired g2/gt table + step/rw
  float* den = (float*)(smem + L_DEN);
  float* num = (float*)(smem + L_NUM);
  float* sa  = (float*)(smem + L_SA);

  int tid = threadIdx.x;
  int lane = tid & 63, wv = tid >> 6;
  int quad = lane >> 4, col = lane & 15;

  // XCD-chunked bijective swizzle (1024 blocks, 8 XCDs)
  int hwid = blockIdx.x + (blockIdx.y << 3) + (blockIdx.z << 8);
  int virt = ((hwid & 7) << 7) + (hwid >> 3);
  int bb = virt >> 8, y0 = ((virt >> 3) & 31) * 4, x0 = (virt & 7) * 16;

  int ub = x0 - 8;

  const float* fimg = f_in + (size_t)bb * CHW;
  const float* rimg = ref  + (size_t)bb * CHW;

  // ---- prefetch registers (PRE=1: bf16 chunks; PRE=0: raw fp32) ----
  s8v pT0, pT1, pU0, pU1;
  float4 pF0, pF1, pF2, pF3;

  auto loadT = [&](int r){
    if constexpr (PRE){
      const short* tb = refT + (size_t)(bb*HH + r) * WW * CC;
      { int e = tid;       int ua = ub + (e >> 4);
        pT0 = (ua >= 0 && ua < WW)
              ? *(const s8v*)(tb + (size_t)ua*CC + ((e & 15) << 3)) : (s8v)(short)0; }
      { int e = tid + 256; int ua = ub + (e >> 4);
        pT1 = (ua >= 0 && ua < WW)
              ? *(const s8v*)(tb + (size_t)ua*CC + ((e & 15) << 3)) : (s8v)(short)0; }
    } else {
      const float* rb = rimg + (size_t)r * WW;
      float4 z; z.x = z.y = z.z = z.w = 0.f;
      { int e = tid;       int ua = ub + (e & 7)*4;
        pF0 = (ua >= 0 && ua + 4 <= WW) ? *(const float4*)(rb + (size_t)(e >> 3)*HW + ua) : z; }
      { int e = tid + 256; int ua = ub + (e & 7)*4;
        pF1 = (ua >= 0 && ua + 4 <= WW) ? *(const float4*)(rb + (size_t)(e >> 3)*HW + ua) : z; }
      { int e = tid + 512; int ua = ub + (e & 7)*4;
        pF2 = (ua >= 0 && ua + 4 <= WW) ? *(const float4*)(rb + (size_t)(e >> 3)*HW + ua) : z; }
      { int e = tid + 768; int ua = ub + (e & 7)*4;
        pF3 = (ua >= 0 && ua + 4 <= WW) ? *(const float4*)(rb + (size_t)(e >> 3)*HW + ua) : z; }
    }
  };
  auto loadU = [&](int r){
    if constexpr (PRE){
      const short* ubp = refU + (size_t)(bb*HH + r) * CC * WW;
      { int e = tid;       int ua = ub + ((e & 3) << 3);
        pU0 = (ua >= 0 && ua + 8 <= WW)
              ? *(const s8v*)(ubp + (size_t)(e >> 2)*WW + ua) : (s8v)(short)0; }
      { int e = tid + 256; int ua = ub + ((e & 3) << 3);
        pU1 = (ua >= 0 && ua + 8 <= WW)
              ? *(const s8v*)(ubp + (size_t)(e >> 2)*WW + ua) : (s8v)(short)0; }
    }
  };
  auto writeRowA = [&](){
    if constexpr (PRE){
      { int e = tid;       *(s8v*)&uc[(e >> 4)*CP + ((e & 15) << 3)] = pT0; }
      { int e = tid + 256; *(s8v*)&uc[(e >> 4)*CP + ((e & 15) << 3)] = pT1; }
      { int e = tid;       *(s8v*)&cu[(e >> 2)*UPITCH + ((e & 3) << 3)] = pU0; }
      { int e = tid + 256; *(s8v*)&cu[(e >> 2)*UPITCH + ((e & 3) << 3)] = pU1; }
    } else {
      float4 vv[4] = {pF0, pF1, pF2, pF3};
      #pragma unroll
      for (int k = 0; k < 4; k++){
        int e4 = tid + (k << 8);
        int u4 = (e4 & 7) * 4, c = e4 >> 3;
        short h0 = f2bf(vv[k].x), h1 = f2bf(vv[k].y),
              h2 = f2bf(vv[k].z), h3 = f2bf(vv[k].w);
        uc[(u4+0)*CP + c] = h0; uc[(u4+1)*CP + c] = h1;
        uc[(u4+2)*CP + c] = h2; uc[(u4+3)*CP + c] = h3;
        s4v pk = {h0, h1, h2, h3};
        *(s4v*)&cu[c*UPITCH + u4] = pk;
      }
    }
  };
  auto writeRowB = [&](){
    if constexpr (PRE){
      { int e = tid;       *(s8v*)&uc[(e >> 4)*CP + ((e & 15) << 3)] = pT0; }
      { int e = tid + 256; *(s8v*)&uc[(e >> 4)*CP + ((e & 15) << 3)] = pT1; }
    } else {
      float4 vv[4] = {pF0, pF1, pF2, pF3};
      #pragma unroll
      for (int k = 0; k < 4; k++){
        int e4 = tid + (k << 8);
        int u4 = (e4 & 7) * 4, c = e4 >> 3;
        uc[(u4+0)*CP + c] = f2bf(vv[k].x); uc[(u4+1)*CP + c] = f2bf(vv[k].y);
        uc[(u4+2)*CP + c] = f2bf(vv[k].z); uc[(u4+3)*CP + c] = f2bf(vv[k].w);
      }
    }
  };

  // prologue: loads for rr=0 (row y0-4), in flight under coef copy + A-frag build
  if (y0 - 4 >= 0){ loadT(y0 - 4); loadU(y0 - 4); }

  for (int e = tid; e < 512; e += 256) s_cf[e] = coef[e];

  // ---- A-frags (f at row y0+wv, hi/lo split) straight from global ----
  int fy = y0 + wv;
  s8v a_hi[4], a_lo[4];
  #pragma unroll
  for (int kc = 0; kc < 4; kc++){
    short th[8], tl[8];
    #pragma unroll
    for (int j = 0; j < 8; j++){
      int c = kc*32 + quad*8 + j;
      float v = fimg[(size_t)c * HW + fy * WW + x0 + col];
      short h = f2bf(v);
      th[j] = h; tl[j] = f2bf(v - bf2f(h));
    }
    a_hi[kc] = *(const s8v*)th;
    a_lo[kc] = *(const s8v*)tl;
  }

  f4v D[8];
  #pragma unroll
  for (int i = 0; i < 8; i++) D[i] = (f4v)0.f;

  // sign FIFO: 9 x 16-bit packs in 3 u64 (push A, pop B, same order)
  unsigned long long f0 = 0ull, f1 = 0ull, f2 = 0ull;

  // =================== phase A: corr1 -> P -> corr_t ===================
  for (int rr = 0; rr < 12; rr++){
    int r = y0 + rr - 4;
    bool rv = (r >= 0) && (r < HH);
    __syncthreads();
    if (rv) writeRowA();
    __syncthreads();
    // issue next row's loads NOW: the vmcnt(0)-drain at the next barrier
    // is then covered by the compute below
    if (rr < 11){
      int rn = r + 1;
      if (rn >= 0 && rn < HH){ loadT(rn); loadU(rn); }
    }
    int dy = rr - wv;
    if (dy >= 0 && dy <= 8){
      unsigned pack = 0u;
      if (rv){
        // corr1: C[x,u] = sum_c (f_hi+f_lo)[x,c] * ref[c,u]
        f4v C0 = (f4v)0.f, C1 = (f4v)0.f;
        #pragma unroll
        for (int kc = 0; kc < 4; kc++){
          s8v b0 = *(const s8v*)&uc[col*CP      + kc*32 + quad*8];
          s8v b1 = *(const s8v*)&uc[(16+col)*CP + kc*32 + quad*8];
          C0 = __builtin_amdgcn_mfma_f32_16x16x32_bf16(a_hi[kc], b0, C0, 0,0,0);
          C0 = __builtin_amdgcn_mfma_f32_16x16x32_bf16(a_lo[kc], b0, C0, 0,0,0);
          C1 = __builtin_amdgcn_mfma_f32_16x16x32_bf16(a_hi[kc], b1, C1, 0,0,0);
          C1 = __builtin_amdgcn_mfma_f32_16x16x32_bf16(a_lo[kc], b1, C1, 0,0,0);
        }
        // scores -> sign pack (regs) + mapped -> P[x,u]
        #pragma unroll
        for (int nt = 0; nt < 2; nt++){
          f4v Cv = nt ? C1 : C0;
          #pragma unroll
          for (int reg = 0; reg < 4; reg++){
            int x  = quad*4 + reg;            // C/D row = (lane>>4)*4 + reg
            int up = nt*16 + col;             // C/D col = lane&15 (+tile)
            int dxm = up - x - 4;
            float m = 0.f;
            if ((unsigned)dxm <= 8u){
              float s = Cv[reg];
              int d = dy*9 + dxm;
              unsigned pos = (s > 0.f) ? 1u : 0u;
              unsigned neg = (s < 0.f) ? 1u : 0u;
              int cse = pos ? 0 : (neg ? 1 : 2);
              float2 gg = *(const float2*)&s_cf[(d*3 + cse)*2];
              m = fmaf(gg.x, s, -gg.y);
              pack |= (pos | (neg << 1)) << ((nt*4 + reg) * 2);
            }
            Pm[(wv*16 + x)*PP + up] = f2bf(m);
          }
        }
        // wave-local LDS handoff (keep global prefetch in flight)
        asm volatile("s_waitcnt lgkmcnt(0)" ::: "memory");
        __builtin_amdgcn_sched_barrier(0);
        // corr_t: D[x,c] += sum_u P[x,u] * ref[u,c]
        s8v pa = *(const s8v*)&Pm[(wv*16 + col)*PP + quad*8];
        #pragma unroll
        for (int ct = 0; ct < 8; ct++){
          s8v bc = *(const s8v*)&cu[(ct*16 + col)*UPITCH + quad*8];
          D[ct] = __builtin_amdgcn_mfma_f32_16x16x32_bf16(pa, bc, D[ct], 0,0,0);
        }
      }
      // FIFO push (always when dy in window, so A/B stay aligned)
      f0 = (f0 >> 16) | (f1 << 48);
      f1 = (f1 >> 16) | (f2 << 48);
      f2 = (f2 >> 16) | ((unsigned long long)pack << 48);
    }
  }

  // phase-B prologue loads fly under the epilogue work
  if (y0 - 4 >= 0) loadT(y0 - 4);

  // ---- epilogue-1: fgs = bf16(D + rw*f) (overlays cu+Pm), then num ----
  float rw = s_cf[501];
  __syncthreads();
  #pragma unroll
  for (int ct = 0; ct < 8; ct++){
    #pragma unroll
    for (int reg = 0; reg < 4; reg++){
      int x = quad*4 + reg, c = ct*16 + col;
      float fv = fimg[(size_t)c * HW + fy * WW + x0 + x];
      fgs[(wv*16 + x)*CP + c] = f2bf(D[ct][reg] + rw * fv);
    }
  }
  __syncthreads();
  if (tid < 64){
    float s = 0.f;
    #pragma unroll
    for (int kc = 0; kc < 16; kc++){
      s8v v = *(const s8v*)&fgs[tid*CP + kc*8];
      #pragma unroll
      for (int j = 0; j < 8; j++){ float f = bf2f(v[j]); s += f*f; }
    }
    num[tid] = s;
  }

  // =================== phase B: corr(fgrad) -> den -> update ===================
  s8v ga_[4];
  #pragma unroll
  for (int kc = 0; kc < 4; kc++)
    ga_[kc] = *(const s8v*)&fgs[(wv*16 + col)*CP + kc*32 + quad*8];

  float dacc[4] = {0.f, 0.f, 0.f, 0.f};    // per-thread den partials (by reg)

  for (int rr = 0; rr < 12; rr++){
    int r = y0 + rr - 4;
    bool rv = (r >= 0) && (r < HH);
    __syncthreads();
    if (rv) writeRowB();
    __syncthreads();
    if (rr < 11){
      int rn = r + 1;
      if (rn >= 0 && rn < HH) loadT(rn);
    }
    int dy = rr - wv;
    if (dy >= 0 && dy <= 8){
      // FIFO pop (mirrors phase-A push order)
      unsigned pack = (unsigned)(f0 >> 48) & 0xFFFFu;
      f0 = (f0 >> 16) | (f1 << 48);
      f1 = (f1 >> 16) | (f2 << 48);
      f2 >>= 16;
      if (rv){
        f4v C0 = (f4v)0.f, C1 = (f4v)0.f;
        #pragma unroll
        for (int kc = 0; kc < 4; kc++){
          s8v b0 = *(const s8v*)&uc[col*CP      + kc*32 + quad*8];
          s8v b1 = *(const s8v*)&uc[(16+col)*CP + kc*32 + quad*8];
          C0 = __builtin_amdgcn_mfma_f32_16x16x32_bf16(ga_[kc], b0, C0, 0,0,0);
          C1 = __builtin_amdgcn_mfma_f32_16x16x32_bf16(ga_[kc], b1, C1, 0,0,0);
        }
        #pragma unroll
        for (int nt = 0; nt < 2; nt++){
          f4v Cv = nt ? C1 : C0;
          #pragma unroll
          for (int reg = 0; reg < 4; reg++){
            int x  = quad*4 + reg;
            int up = nt*16 + col;
            int dxm = up - x - 4;
            if ((unsigned)dxm <= 8u){
              int d = dy*9 + dxm;
              unsigned b2 = pack >> ((nt*4 + reg) * 2);
              int cse = (b2 & 1u) ? 0 : ((b2 & 2u) ? 1 : 2);
              float g2 = s_cf[(d*3 + cse)*2];
              float t  = Cv[reg];
              dacc[reg] = fmaf(g2 * t, t, dacc[reg]);
            }
          }
        }
      }
    }
  }

  // den: reduce partials across the 16 col-lanes of each quad (no atomics)
  #pragma unroll
  for (int reg = 0; reg < 4; reg++){
    float v = dacc[reg];
    v += __shfl_xor(v, 1);
    v += __shfl_xor(v, 2);
    v += __shfl_xor(v, 4);
    v += __shfl_xor(v, 8);
    if (col == 0) den[wv*16 + quad*4 + reg] = v;
  }

  __syncthreads();
  if (tid < 64){
    float step = s_cf[500];
    float alpha = num[tid] / fmaxf(den[tid] + rw*num[tid], 1e-8f);
    sa[tid] = step * alpha;
  }
  __syncthreads();

  // ---- update: f_out = f - step*alpha*fgrad (coalesced) ----
  float* oimg = f_out + (size_t)bb * CHW;
  for (int e = tid; e < 8192; e += 256){
    int x = e & 15, y = (e >> 4) & 3, c = e >> 6;
    size_t gi = (size_t)c * HW + (y0 + y) * WW + x0 + x;
    float v = fimg[gi] - sa[y*16 + x] * bf2f(fgs[(y*16 + x)*CP + c]);
    oimg[gi] = v;
  }
}

// ---------------------------------------------------------------------------
extern "C" void kernel_launch(void* const* d_in, const int* in_sizes, int n_in,
                              void* d_out, int out_size, void* d_ws, size_t ws_size,
                              hipStream_t stream) {
  const float* filter_map = (const float*)d_in[0];
  const float* ref        = (const float*)d_in[1];
  const float* label_w    = (const float*)d_in[2];
  const float* spatial_w  = (const float*)d_in[3];
  const float* mask_w     = (const float*)d_in[4];
  const float* lsl        = (const float*)d_in[5];
  const float* freg       = (const float*)d_in[6];

  float* coef = (float*)d_ws;      // coef tables (64 KB region reserved)
  float* fbuf = (float*)d_out;     // evolving filter lives in d_out (fp32)

  // bf16 pre-transposed ref copies in workspace (guarded by ws_size)
  short* refT = (short*)((char*)d_ws + 65536);
  short* refU = refT + (size_t)BB * CHW;
  size_t need = 65536 + 2 * (size_t)BB * CHW * sizeof(short);
  bool pre = (ws_size >= need);

  coef_kernel<<<dim3(1), dim3(128), 0, stream>>>(label_w, spatial_w, mask_w, lsl, freg, coef);
  if (pre)
    cvt_kernel<<<dim3(HH, BB), dim3(256), 0, stream>>>(ref, refT, refU);

  dim3 grid(8, 32, BB);   // 16-col x-tiles, 4-row y-bands, batch
  for (int it = 0; it < 3; it++){
    const float* fsrc = (it == 0) ? filter_map : (const float*)fbuf;
    if (pre) kF<1><<<grid, 256, 0, stream>>>(fsrc, ref, refT, refU, coef, fbuf);
    else     kF<0><<<grid, 256, 0, stream>>>(fsrc, ref, refT, refU, coef, fbuf);
  }
}